// Round 6
// baseline (200.750 us; speedup 1.0000x reference)
//
#include <hip/hip_runtime.h>
#include <stdint.h>
#include <stddef.h>

#define EMB 1024
#define NTOK 16384

typedef __attribute__((ext_vector_type(8))) short short8;
typedef __attribute__((ext_vector_type(4))) float floatx4;

__device__ __forceinline__ unsigned short f2bf(float f) {
    union { float f; unsigned int u; } v; v.f = f;
    unsigned int u = v.u;
    unsigned int r = (u + 0x7fffu + ((u >> 16) & 1u)) >> 16;
    return (unsigned short)r;
}
__device__ __forceinline__ float bf2f(unsigned short s) {
    union { unsigned int u; float f; } v; v.u = ((unsigned int)s) << 16;
    return v.f;
}

__device__ __forceinline__ void gload16(const void* g, void* l) {
    __builtin_amdgcn_global_load_lds(
        (const __attribute__((address_space(1))) void*)g,
        (__attribute__((address_space(3))) void*)l, 16, 0, 0);
}

// opaque LDS b128 read: base VGPR (bytes) + compile-time immediate offset
#define DSR(dst, base, imm) \
    asm volatile("ds_read_b128 %0, %1 offset:%c2" : "=v"(dst) : "v"(base), "i"(imm))

// ---------------- fp32 -> bf16 conversion ----------------
__global__ void cvt_kernel(const float* __restrict__ in,
                           unsigned short* __restrict__ out, int n4) {
    int idx = blockIdx.x * blockDim.x + threadIdx.x;
    int stride = gridDim.x * blockDim.x;
    for (int i = idx; i < n4; i += stride) {
        float4 f = reinterpret_cast<const float4*>(in)[i];
        ushort4 o;
        o.x = f2bf(f.x); o.y = f2bf(f.y); o.z = f2bf(f.z); o.w = f2bf(f.w);
        reinterpret_cast<ushort4*>(out)[i] = o;
    }
}

__global__ void cvt4_kernel(const float* __restrict__ s0, const float* __restrict__ s1,
                            const float* __restrict__ s2, const float* __restrict__ s3,
                            unsigned short* __restrict__ out) {
    int idx = blockIdx.x * blockDim.x + threadIdx.x;
    const int total = 4 << 18;
    int stride = gridDim.x * blockDim.x;
    for (int i = idx; i < total; i += stride) {
        int w = i >> 18, r = i & ((1 << 18) - 1);
        const float* s = (w == 0) ? s0 : (w == 1) ? s1 : (w == 2) ? s2 : s3;
        float4 f = reinterpret_cast<const float4*>(s)[r];
        ushort4 o;
        o.x = f2bf(f.x); o.y = f2bf(f.y); o.z = f2bf(f.z); o.w = f2bf(f.w);
        reinterpret_cast<ushort4*>(out)[i] = o;
    }
}

__global__ void bias_cat_kernel(const float* __restrict__ b0,
                                const float* __restrict__ b1,
                                const float* __restrict__ b2,
                                float* __restrict__ out) {
    int i = blockIdx.x * blockDim.x + threadIdx.x;
    float v = (i < 1024) ? b0[i] : (i < 2048 ? b1[i - 1024] : b2[i - 2048]);
    out[i] = v;
}

// ---------------- 256x256 bf16 GEMM, asm-pinned pipeline ----------------
// BK=64, 512 threads (8 waves 2Mx4N), LDS 128 KB double-buffered.
// Regions (ushort elems, buffer base b*32768):
//   A-kh0: +0   A-kh1: +8192   B-kh0: +16384   B-kh1: +24576
// 16B k-slots XOR-swizzled by ((row>>1)&3) on GLOBAL source + LDS read addr.
// Fragment reads are inline-asm ds_read_b128 (opaque to compiler) so hipcc
// cannot insert conservative vmcnt(0) drains; the ONLY vm waits are the
// counted vmcnt(4) at the two sync points per K-tile. rule-18 pinning:
// lgkmcnt(0) + sched_barrier(0) before each MFMA cluster.
__device__ __forceinline__ void store_val(float* C, size_t idx, float v) { C[idx] = v; }
__device__ __forceinline__ void store_val(unsigned short* C, size_t idx, float v) { C[idx] = f2bf(v); }

template<typename OUT_T>
__global__ __launch_bounds__(512, 2)
void gemm256(const unsigned short* __restrict__ A,
             const unsigned short* __restrict__ B,
             const float* __restrict__ bias,
             OUT_T* __restrict__ C,
             int K, int Nc, int grid_m)
{
    __shared__ unsigned short lds[65536];  // 128 KB

    // XCD-stripe mapping: XCD owns (grid_m/8) m-tiles, n fastest.
    const int bid = blockIdx.x;
    const int x = bid & 7;
    const int w = bid >> 3;
    const int ms = grid_m >> 3;
    const int m0 = (x * ms + (w & (ms - 1))) * 256;
    const int n0 = (w / ms) * 256;

    const int tid  = threadIdx.x;
    const int lane = tid & 63;
    const int wid  = tid >> 6;
    const int wm = (wid >> 2) * 128;
    const int wn = (wid & 3) * 64;
    const int rr = lane & 15;
    const int klo = (((lane >> 4) ^ ((rr >> 1) & 3)) << 3);

    const int aro = (wm + rr) * 32 + klo;            // elems, A kh0 frag base
    const int bro = 16384 + (wn + rr) * 32 + klo;    // elems, B kh0 frag base

    const unsigned ldsb = (unsigned)(uintptr_t)(void*)&lds[0];

    const unsigned short* pA[2];
    const unsigned short* pB[2];
    int ldst[2];
#pragma unroll
    for (int l = 0; l < 2; ++l) {
        const int P16  = l * 512 + tid;
        const int rowS = P16 >> 2;
        const int colel = (((P16 & 3) ^ ((rowS >> 1) & 3)) << 3);
        pA[l] = A + (size_t)(m0 + rowS) * K + colel;
        pB[l] = B + (size_t)(n0 + rowS) * K + colel;
        ldst[l] = P16 * 8;
    }

    floatx4 acc[8][4];
#pragma unroll
    for (int i = 0; i < 8; ++i)
#pragma unroll
        for (int j = 0; j < 4; ++j)
            acc[i][j] = (floatx4){0.f, 0.f, 0.f, 0.f};

    const int NT = K >> 6;

    // ---- prologue: stage tile 0 into buf0, drain ----
#pragma unroll
    for (int l = 0; l < 2; ++l) {
        gload16(pA[l],      &lds[0     + ldst[l]]);
        gload16(pA[l] + 32, &lds[8192  + ldst[l]]);
        gload16(pB[l],      &lds[16384 + ldst[l]]);
        gload16(pB[l] + 32, &lds[24576 + ldst[l]]);
    }
    __builtin_amdgcn_sched_barrier(0);
    asm volatile("s_waitcnt vmcnt(0)");
    __builtin_amdgcn_s_barrier();
    __builtin_amdgcn_sched_barrier(0);

    for (int t = 0; t < NT; ++t) {
        const int cur = (t & 1) * 32768;
        const int nxt = cur ^ 32768;
        const int ktn = (t + 1 < NT) ? (t + 1) * 64 : 0;
        const unsigned abA = ldsb + (unsigned)(2 * (cur + aro));  // bytes
        const unsigned abB = ldsb + (unsigned)(2 * (cur + bro));

        short8 a0[4], a1[4], bb[4];

        // ============ region 1: kh0 ============
        gload16(pA[0] + ktn, &lds[nxt + ldst[0]]);           // R0 = A-kh0(next)
        gload16(pA[1] + ktn, &lds[nxt + ldst[1]]);
        gload16(pB[0] + ktn, &lds[nxt + 16384 + ldst[0]]);   // R1 = B-kh0(next)
        gload16(pB[1] + ktn, &lds[nxt + 16384 + ldst[1]]);
        DSR(a0[0], abA, 0);    DSR(a0[1], abA, 1024);
        DSR(a0[2], abA, 2048); DSR(a0[3], abA, 3072);
        DSR(bb[0], abB, 0);    DSR(bb[1], abB, 1024);
        DSR(bb[2], abB, 2048); DSR(bb[3], abB, 3072);
        DSR(a1[0], abA, 4096); DSR(a1[1], abA, 5120);
        DSR(a1[2], abA, 6144); DSR(a1[3], abA, 7168);
        asm volatile("s_waitcnt lgkmcnt(0)");
        __builtin_amdgcn_sched_barrier(0);
        __builtin_amdgcn_s_setprio(1);
#pragma unroll
        for (int j = 0; j < 4; ++j)
#pragma unroll
            for (int i = 0; i < 4; ++i)
                acc[i][j] = __builtin_amdgcn_mfma_f32_16x16x32_bf16(a0[i], bb[j], acc[i][j], 0, 0, 0);
#pragma unroll
        for (int j = 0; j < 4; ++j)
#pragma unroll
            for (int i = 0; i < 4; ++i)
                acc[4 + i][j] = __builtin_amdgcn_mfma_f32_16x16x32_bf16(a1[i], bb[j], acc[4 + i][j], 0, 0, 0);
        __builtin_amdgcn_s_setprio(0);
        __builtin_amdgcn_sched_barrier(0);
        // drain prev-issued kh1 granules of THIS tile; leaves R0,R1 in flight
        asm volatile("s_waitcnt vmcnt(4)");
        __builtin_amdgcn_s_barrier();
        __builtin_amdgcn_sched_barrier(0);

        // ============ region 2: kh1 ============
        gload16(pA[0] + ktn + 32, &lds[nxt + 8192 + ldst[0]]);   // R2 = A-kh1(next)
        gload16(pA[1] + ktn + 32, &lds[nxt + 8192 + ldst[1]]);
        gload16(pB[0] + ktn + 32, &lds[nxt + 24576 + ldst[0]]);  // R3 = B-kh1(next)
        gload16(pB[1] + ktn + 32, &lds[nxt + 24576 + ldst[1]]);
        DSR(a0[0], abA, 16384 + 0);    DSR(a0[1], abA, 16384 + 1024);
        DSR(a0[2], abA, 16384 + 2048); DSR(a0[3], abA, 16384 + 3072);
        DSR(bb[0], abB, 16384 + 0);    DSR(bb[1], abB, 16384 + 1024);
        DSR(bb[2], abB, 16384 + 2048); DSR(bb[3], abB, 16384 + 3072);
        DSR(a1[0], abA, 20480 + 0);    DSR(a1[1], abA, 20480 + 1024);
        DSR(a1[2], abA, 20480 + 2048); DSR(a1[3], abA, 20480 + 3072);
        asm volatile("s_waitcnt lgkmcnt(0)");
        __builtin_amdgcn_sched_barrier(0);
        __builtin_amdgcn_s_setprio(1);
#pragma unroll
        for (int j = 0; j < 4; ++j)
#pragma unroll
            for (int i = 0; i < 4; ++i)
                acc[i][j] = __builtin_amdgcn_mfma_f32_16x16x32_bf16(a0[i], bb[j], acc[i][j], 0, 0, 0);
#pragma unroll
        for (int j = 0; j < 4; ++j)
#pragma unroll
            for (int i = 0; i < 4; ++i)
                acc[4 + i][j] = __builtin_amdgcn_mfma_f32_16x16x32_bf16(a1[i], bb[j], acc[4 + i][j], 0, 0, 0);
        __builtin_amdgcn_s_setprio(0);
        __builtin_amdgcn_sched_barrier(0);
        // drain this tile's R0,R1 (next tile's kh0); leaves R2,R3 in flight
        asm volatile("s_waitcnt vmcnt(4)");
        __builtin_amdgcn_s_barrier();
        __builtin_amdgcn_sched_barrier(0);
    }

    // ---- epilogue ----
    const int cn  = lane & 15;
    const int cm4 = (lane >> 4) * 4;
    float bv[4];
#pragma unroll
    for (int j = 0; j < 4; ++j) bv[j] = bias[n0 + wn + j * 16 + cn];
#pragma unroll
    for (int ai = 0; ai < 8; ++ai) {
        const int row = m0 + wm + (ai >> 2) * 64 + (ai & 3) * 16 + cm4;
#pragma unroll
        for (int j = 0; j < 4; ++j) {
            const int col = n0 + wn + j * 16 + cn;
#pragma unroll
            for (int r = 0; r < 4; ++r)
                store_val(C, (size_t)(row + r) * Nc + col, acc[ai][j][r] + bv[j]);
        }
    }
}

// ---------------- per-token 16-head attention (wave per token) ----------------
#define ROWP 72

__global__ __launch_bounds__(256)
void attn_kernel(const unsigned short* __restrict__ QKV,
                 unsigned short* __restrict__ O)
{
    const int wave = threadIdx.x >> 6;
    const int lane = threadIdx.x & 63;
    const int n = blockIdx.x * 4 + wave;

    __shared__ unsigned short lq[4][16 * ROWP];
    __shared__ unsigned short lk[4][16 * ROWP];
    __shared__ unsigned short lv[4][16 * ROWP];
    __shared__ float lp[4][256];

    {
        const unsigned short* gq = QKV + (size_t)n * 3072;
        const unsigned short* gk = gq + 1024;
        const unsigned short* gv = gq + 2048;
        for (int t = lane; t < 128; t += 64) {
            int r = t >> 3, c = t & 7;
            *reinterpret_cast<short8*>(&lq[wave][r * ROWP + c * 8]) =
                *reinterpret_cast<const short8*>(gq + t * 8);
            *reinterpret_cast<short8*>(&lk[wave][r * ROWP + c * 8]) =
                *reinterpret_cast<const short8*>(gk + t * 8);
            *reinterpret_cast<short8*>(&lv[wave][r * ROWP + c * 8]) =
                *reinterpret_cast<const short8*>(gv + t * 8);
        }
    }
    __syncthreads();

    const int g = lane & 15;
    const int a = lane >> 4;

    float kf[64];
#pragma unroll
    for (int c2 = 0; c2 < 8; ++c2) {
        short8 kv = *reinterpret_cast<const short8*>(&lk[wave][g * ROWP + c2 * 8]);
#pragma unroll
        for (int e = 0; e < 8; ++e) kf[c2 * 8 + e] = bf2f((unsigned short)kv[e]);
    }

#pragma unroll
    for (int i = 0; i < 4; ++i) {
        const int h = i * 4 + a;
        float s = 0.f;
#pragma unroll
        for (int c2 = 0; c2 < 8; ++c2) {
            short8 qv = *reinterpret_cast<const short8*>(&lq[wave][h * ROWP + c2 * 8]);
#pragma unroll
            for (int e = 0; e < 8; ++e)
                s = fmaf(bf2f((unsigned short)qv[e]), kf[c2 * 8 + e], s);
        }
        s *= 0.125f;

        float m = s;
#pragma unroll
        for (int o = 1; o < 16; o <<= 1) m = fmaxf(m, __shfl_xor(m, o, 64));
        float p = expf(s - m);
        float sum = p;
#pragma unroll
        for (int o = 1; o < 16; o <<= 1) sum += __shfl_xor(sum, o, 64);
        lp[wave][h * 16 + g] = p / sum;
    }
    __syncthreads();

    const int h = lane >> 2;
    const int db = (lane & 3) * 16;
    float o[16];
#pragma unroll
    for (int e = 0; e < 16; ++e) o[e] = 0.f;

    for (int g2 = 0; g2 < 16; ++g2) {
        const float pw = lp[wave][h * 16 + g2];
        short8 v0 = *reinterpret_cast<const short8*>(&lv[wave][g2 * ROWP + db]);
        short8 v1 = *reinterpret_cast<const short8*>(&lv[wave][g2 * ROWP + db + 8]);
#pragma unroll
        for (int e = 0; e < 8; ++e) {
            o[e]     = fmaf(pw, bf2f((unsigned short)v0[e]), o[e]);
            o[8 + e] = fmaf(pw, bf2f((unsigned short)v1[e]), o[8 + e]);
        }
    }

    short8 o0, o1;
#pragma unroll
    for (int e = 0; e < 8; ++e) {
        o0[e] = (short)f2bf(o[e]);
        o1[e] = (short)f2bf(o[8 + e]);
    }
    unsigned short* dst = O + (size_t)n * EMB + h * 64 + db;
    *reinterpret_cast<short8*>(dst) = o0;
    *reinterpret_cast<short8*>(dst + 8) = o1;
}

// ---------------- launch ----------------
extern "C" void kernel_launch(void* const* d_in, const int* in_sizes, int n_in,
                              void* d_out, int out_size, void* d_ws, size_t ws_size,
                              hipStream_t stream)
{
    const float* src = (const float*)d_in[0];
    const float* Wq  = (const float*)d_in[1];
    const float* bq  = (const float*)d_in[2];
    const float* Wk  = (const float*)d_in[3];
    const float* bk  = (const float*)d_in[4];
    const float* Wv  = (const float*)d_in[5];
    const float* bv  = (const float*)d_in[6];
    const float* Wo  = (const float*)d_in[7];
    const float* bo  = (const float*)d_in[8];
    float* out = (float*)d_out;

    unsigned short* ws = (unsigned short*)d_ws;
    unsigned short* src_bf = ws;                                      // 16384*1024
    unsigned short* wqkv   = src_bf + (size_t)NTOK * EMB;             // 3*1024*1024 (Wq|Wk|Wv)
    unsigned short* wo_bf  = wqkv + (size_t)3 * EMB * EMB;            // 1024*1024 (contiguous after wqkv)
    unsigned short* qkv    = wo_bf + (size_t)EMB * EMB;               // 16384*3072
    unsigned short* ab     = qkv + (size_t)NTOK * 3 * EMB;            // 16384*1024
    float* bias_cat        = (float*)(ab + (size_t)NTOK * EMB);       // 3072 floats

    cvt_kernel<<<2048, 256, 0, stream>>>(src, src_bf, NTOK * EMB / 4);
    cvt4_kernel<<<2048, 256, 0, stream>>>(Wq, Wk, Wv, Wo, wqkv);  // fills wqkv then wo_bf
    bias_cat_kernel<<<12, 256, 0, stream>>>(bq, bk, bv, bias_cat);

    // fused QKV projection: [16384][3072] = src_bf * [3072][1024]^T
    gemm256<unsigned short><<<dim3(64 * 12), 512, 0, stream>>>(
        src_bf, wqkv, bias_cat, qkv, EMB, 3 * EMB, 64);

    attn_kernel<<<NTOK / 4, 256, 0, stream>>>(qkv, ab);

    // output projection: [16384][1024]
    gemm256<float><<<dim3(64 * 4), 512, 0, stream>>>(
        ab, wo_bf, bo, out, EMB, EMB, 64);
}

// Round 9
// 199.520 us; speedup vs baseline: 1.0062x; 1.0062x over previous
//
#include <hip/hip_runtime.h>
#include <stdint.h>
#include <stddef.h>

#define EMB 1024
#define NTOK 16384

typedef __attribute__((ext_vector_type(8))) short short8;
typedef __attribute__((ext_vector_type(4))) float floatx4;

__device__ __forceinline__ unsigned short f2bf(float f) {
    union { float f; unsigned int u; } v; v.f = f;
    unsigned int u = v.u;
    unsigned int r = (u + 0x7fffu + ((u >> 16) & 1u)) >> 16;
    return (unsigned short)r;
}
__device__ __forceinline__ float bf2f(unsigned short s) {
    union { unsigned int u; float f; } v; v.u = ((unsigned int)s) << 16;
    return v.f;
}

__device__ __forceinline__ void gload16(const void* g, void* l) {
    __builtin_amdgcn_global_load_lds(
        (const __attribute__((address_space(1))) void*)g,
        (__attribute__((address_space(3))) void*)l, 16, 0, 0);
}

// ---------------- fp32 -> bf16 conversion ----------------
__global__ void cvt_kernel(const float* __restrict__ in,
                           unsigned short* __restrict__ out, int n4) {
    int idx = blockIdx.x * blockDim.x + threadIdx.x;
    int stride = gridDim.x * blockDim.x;
    for (int i = idx; i < n4; i += stride) {
        float4 f = reinterpret_cast<const float4*>(in)[i];
        ushort4 o;
        o.x = f2bf(f.x); o.y = f2bf(f.y); o.z = f2bf(f.z); o.w = f2bf(f.w);
        reinterpret_cast<ushort4*>(out)[i] = o;
    }
}

__global__ void cvt4_kernel(const float* __restrict__ s0, const float* __restrict__ s1,
                            const float* __restrict__ s2, const float* __restrict__ s3,
                            unsigned short* __restrict__ out) {
    int idx = blockIdx.x * blockDim.x + threadIdx.x;
    const int total = 4 << 18;
    int stride = gridDim.x * blockDim.x;
    for (int i = idx; i < total; i += stride) {
        int w = i >> 18, r = i & ((1 << 18) - 1);
        const float* s = (w == 0) ? s0 : (w == 1) ? s1 : (w == 2) ? s2 : s3;
        float4 f = reinterpret_cast<const float4*>(s)[r];
        ushort4 o;
        o.x = f2bf(f.x); o.y = f2bf(f.y); o.z = f2bf(f.z); o.w = f2bf(f.w);
        reinterpret_cast<ushort4*>(out)[i] = o;
    }
}

__global__ void bias_cat_kernel(const float* __restrict__ b0,
                                const float* __restrict__ b1,
                                const float* __restrict__ b2,
                                float* __restrict__ out) {
    int i = blockIdx.x * blockDim.x + threadIdx.x;
    float v = (i < 1024) ? b0[i] : (i < 2048 ? b1[i - 1024] : b2[i - 2048]);
    out[i] = v;
}

// ---------------- 256x256 bf16 GEMM, 2 sync points per K-tile ----------------
// BK=64, 512 threads (8 waves 2Mx4N), LDS 128 KB double-buffered.
// Regions (ushort elems, buffer base b*32768):
//   A-kh0: +0   A-kh1: +8192   B-kh0: +16384   B-kh1: +24576
// 16B k-slots XOR-swizzled by ((row>>1)&3) on GLOBAL source + LDS read addr.
// XCD mapping v2: each XCD owns (grid_m/8) m-tiles, processed in m-batches of
// FOUR tiles (A-batch = 2 MB, fits the 4 MB XCD L2 WITH slack for B + the C
// write stream), n iterated fully within each batch -> A fetched ~once/batch.
__device__ __forceinline__ void store_val(float* C, size_t idx, float v) { C[idx] = v; }
__device__ __forceinline__ void store_val(unsigned short* C, size_t idx, float v) { C[idx] = f2bf(v); }

template<typename OUT_T>
__global__ __launch_bounds__(512, 2)
void gemm256(const unsigned short* __restrict__ A,
             const unsigned short* __restrict__ B,
             const float* __restrict__ bias,
             OUT_T* __restrict__ C,
             int K, int Nc, int grid_m, int grid_n)
{
    __shared__ unsigned short lds[65536];  // 128 KB

    // XCD m-batch mapping: batches of 4 m-tiles, n fastest within a batch.
    const int bid = blockIdx.x;
    const int x = bid & 7;
    const int w = bid >> 3;
    const int ms = grid_m >> 3;          // m-tiles per XCD (8)
    const int per = 4 * grid_n;          // tiles per m-batch
    const int b  = w / per;
    const int r  = w % per;
    const int m0 = (x * ms + b * 4 + (r & 3)) * 256;
    const int n0 = (r >> 2) * 256;

    const int tid  = threadIdx.x;
    const int lane = tid & 63;
    const int wid  = tid >> 6;
    const int wm = (wid >> 2) * 128;
    const int wn = (wid & 3) * 64;
    const int rr = lane & 15;
    const int klo = (((lane >> 4) ^ ((rr >> 1) & 3)) << 3);

    const int aro = (wm + rr) * 32 + klo;
    const int bro = 16384 + (wn + rr) * 32 + klo;

    const unsigned short* pA[2];
    const unsigned short* pB[2];
    int ldst[2];
#pragma unroll
    for (int l = 0; l < 2; ++l) {
        const int P16  = l * 512 + tid;
        const int rowS = P16 >> 2;
        const int colel = (((P16 & 3) ^ ((rowS >> 1) & 3)) << 3);
        pA[l] = A + (size_t)(m0 + rowS) * K + colel;
        pB[l] = B + (size_t)(n0 + rowS) * K + colel;
        ldst[l] = P16 * 8;
    }

    floatx4 acc[8][4];
#pragma unroll
    for (int i = 0; i < 8; ++i)
#pragma unroll
        for (int j = 0; j < 4; ++j)
            acc[i][j] = (floatx4){0.f, 0.f, 0.f, 0.f};

    const int NT = K >> 6;

    // ---- prologue: stage tile 0 into buf0, drain, read kh0 frags ----
#pragma unroll
    for (int l = 0; l < 2; ++l) {
        gload16(pA[l],      &lds[0     + ldst[l]]);
        gload16(pA[l] + 32, &lds[8192  + ldst[l]]);
        gload16(pB[l],      &lds[16384 + ldst[l]]);
        gload16(pB[l] + 32, &lds[24576 + ldst[l]]);
    }
    asm volatile("s_waitcnt vmcnt(0)" ::: "memory");
    asm volatile("s_barrier" ::: "memory");

    short8 a0[4], a1[4], b0[4];
#pragma unroll
    for (int i = 0; i < 4; ++i)
        a0[i] = *reinterpret_cast<const short8*>(&lds[aro + i * 512]);
#pragma unroll
    for (int j = 0; j < 4; ++j)
        b0[j] = *reinterpret_cast<const short8*>(&lds[bro + j * 512]);

    for (int t = 0; t < NT; ++t) {
        const int cur = (t & 1) * 32768;
        const int nxt = cur ^ 32768;
        const int ktn = (t + 1 < NT) ? (t + 1) * 64 : 0;

        // ============ region 1: kh0 (a0,b0 already in regs) ============
        gload16(pA[0] + ktn, &lds[nxt + ldst[0]]);           // R0 = A-kh0(next)
        gload16(pA[1] + ktn, &lds[nxt + ldst[1]]);
        gload16(pB[0] + ktn, &lds[nxt + 16384 + ldst[0]]);   // R1 = B-kh0(next)
        gload16(pB[1] + ktn, &lds[nxt + 16384 + ldst[1]]);
#pragma unroll
        for (int i = 0; i < 4; ++i)                          // rh1 of kh0
            a1[i] = *reinterpret_cast<const short8*>(&lds[cur + aro + 2048 + i * 512]);
        __builtin_amdgcn_s_setprio(1);
#pragma unroll
        for (int j = 0; j < 4; ++j)
#pragma unroll
            for (int i = 0; i < 4; ++i)
                acc[i][j] = __builtin_amdgcn_mfma_f32_16x16x32_bf16(a0[i], b0[j], acc[i][j], 0, 0, 0);
#pragma unroll
        for (int j = 0; j < 4; ++j)
#pragma unroll
            for (int i = 0; i < 4; ++i)
                acc[4 + i][j] = __builtin_amdgcn_mfma_f32_16x16x32_bf16(a1[i], b0[j], acc[4 + i][j], 0, 0, 0);
        __builtin_amdgcn_s_setprio(0);
        // drain prev tile's R2,R3 (this tile's kh1 regions); leaves R0,R1 in flight
        asm volatile("s_waitcnt vmcnt(4)" ::: "memory");
        asm volatile("s_barrier" ::: "memory");

        // ============ region 2: kh1 ============
        gload16(pA[0] + ktn + 32, &lds[nxt + 8192 + ldst[0]]);   // R2 = A-kh1(next)
        gload16(pA[1] + ktn + 32, &lds[nxt + 8192 + ldst[1]]);
        gload16(pB[0] + ktn + 32, &lds[nxt + 24576 + ldst[0]]);  // R3 = B-kh1(next)
        gload16(pB[1] + ktn + 32, &lds[nxt + 24576 + ldst[1]]);
#pragma unroll
        for (int i = 0; i < 4; ++i)
            a0[i] = *reinterpret_cast<const short8*>(&lds[cur + 8192 + aro + i * 512]);
#pragma unroll
        for (int j = 0; j < 4; ++j)
            b0[j] = *reinterpret_cast<const short8*>(&lds[cur + 8192 + bro + j * 512]);
#pragma unroll
        for (int i = 0; i < 4; ++i)
            a1[i] = *reinterpret_cast<const short8*>(&lds[cur + 8192 + aro + 2048 + i * 512]);
        __builtin_amdgcn_s_setprio(1);
#pragma unroll
        for (int j = 0; j < 4; ++j)
#pragma unroll
            for (int i = 0; i < 4; ++i)
                acc[i][j] = __builtin_amdgcn_mfma_f32_16x16x32_bf16(a0[i], b0[j], acc[i][j], 0, 0, 0);
#pragma unroll
        for (int j = 0; j < 4; ++j)
#pragma unroll
            for (int i = 0; i < 4; ++i)
                acc[4 + i][j] = __builtin_amdgcn_mfma_f32_16x16x32_bf16(a1[i], b0[j], acc[4 + i][j], 0, 0, 0);
        __builtin_amdgcn_s_setprio(0);
        // drain this tile's R0,R1 (next tile's kh0 regions); leaves R2,R3 in flight
        asm volatile("s_waitcnt vmcnt(4)" ::: "memory");
        asm volatile("s_barrier" ::: "memory");
        // read-ahead next tile's kh0 fragments
#pragma unroll
        for (int i = 0; i < 4; ++i)
            a0[i] = *reinterpret_cast<const short8*>(&lds[nxt + aro + i * 512]);
#pragma unroll
        for (int j = 0; j < 4; ++j)
            b0[j] = *reinterpret_cast<const short8*>(&lds[nxt + bro + j * 512]);
    }

    // ---- epilogue ----
    const int cn  = lane & 15;
    const int cm4 = (lane >> 4) * 4;
    float bv[4];
#pragma unroll
    for (int j = 0; j < 4; ++j) bv[j] = bias[n0 + wn + j * 16 + cn];
#pragma unroll
    for (int ai = 0; ai < 8; ++ai) {
        const int row = m0 + wm + (ai >> 2) * 64 + (ai & 3) * 16 + cm4;
#pragma unroll
        for (int j = 0; j < 4; ++j) {
            const int col = n0 + wn + j * 16 + cn;
#pragma unroll
            for (int r = 0; r < 4; ++r)
                store_val(C, (size_t)(row + r) * Nc + col, acc[ai][j][r] + bv[j]);
        }
    }
}

// ---------------- per-token 16-head attention (wave per token) ----------------
#define ROWP 72

__global__ __launch_bounds__(256)
void attn_kernel(const unsigned short* __restrict__ QKV,
                 unsigned short* __restrict__ O)
{
    const int wave = threadIdx.x >> 6;
    const int lane = threadIdx.x & 63;
    const int n = blockIdx.x * 4 + wave;

    __shared__ unsigned short lq[4][16 * ROWP];
    __shared__ unsigned short lk[4][16 * ROWP];
    __shared__ unsigned short lv[4][16 * ROWP];
    __shared__ float lp[4][256];

    {
        const unsigned short* gq = QKV + (size_t)n * 3072;
        const unsigned short* gk = gq + 1024;
        const unsigned short* gv = gq + 2048;
        for (int t = lane; t < 128; t += 64) {
            int r = t >> 3, c = t & 7;
            *reinterpret_cast<short8*>(&lq[wave][r * ROWP + c * 8]) =
                *reinterpret_cast<const short8*>(gq + t * 8);
            *reinterpret_cast<short8*>(&lk[wave][r * ROWP + c * 8]) =
                *reinterpret_cast<const short8*>(gk + t * 8);
            *reinterpret_cast<short8*>(&lv[wave][r * ROWP + c * 8]) =
                *reinterpret_cast<const short8*>(gv + t * 8);
        }
    }
    __syncthreads();

    const int g = lane & 15;
    const int a = lane >> 4;

    float kf[64];
#pragma unroll
    for (int c2 = 0; c2 < 8; ++c2) {
        short8 kv = *reinterpret_cast<const short8*>(&lk[wave][g * ROWP + c2 * 8]);
#pragma unroll
        for (int e = 0; e < 8; ++e) kf[c2 * 8 + e] = bf2f((unsigned short)kv[e]);
    }

#pragma unroll
    for (int i = 0; i < 4; ++i) {
        const int h = i * 4 + a;
        float s = 0.f;
#pragma unroll
        for (int c2 = 0; c2 < 8; ++c2) {
            short8 qv = *reinterpret_cast<const short8*>(&lq[wave][h * ROWP + c2 * 8]);
#pragma unroll
            for (int e = 0; e < 8; ++e)
                s = fmaf(bf2f((unsigned short)qv[e]), kf[c2 * 8 + e], s);
        }
        s *= 0.125f;

        float m = s;
#pragma unroll
        for (int o = 1; o < 16; o <<= 1) m = fmaxf(m, __shfl_xor(m, o, 64));
        float p = expf(s - m);
        float sum = p;
#pragma unroll
        for (int o = 1; o < 16; o <<= 1) sum += __shfl_xor(sum, o, 64);
        lp[wave][h * 16 + g] = p / sum;
    }
    __syncthreads();

    const int h = lane >> 2;
    const int db = (lane & 3) * 16;
    float o[16];
#pragma unroll
    for (int e = 0; e < 16; ++e) o[e] = 0.f;

    for (int g2 = 0; g2 < 16; ++g2) {
        const float pw = lp[wave][h * 16 + g2];
        short8 v0 = *reinterpret_cast<const short8*>(&lv[wave][g2 * ROWP + db]);
        short8 v1 = *reinterpret_cast<const short8*>(&lv[wave][g2 * ROWP + db + 8]);
#pragma unroll
        for (int e = 0; e < 8; ++e) {
            o[e]     = fmaf(pw, bf2f((unsigned short)v0[e]), o[e]);
            o[8 + e] = fmaf(pw, bf2f((unsigned short)v1[e]), o[8 + e]);
        }
    }

    short8 o0, o1;
#pragma unroll
    for (int e = 0; e < 8; ++e) {
        o0[e] = (short)f2bf(o[e]);
        o1[e] = (short)f2bf(o[8 + e]);
    }
    unsigned short* dst = O + (size_t)n * EMB + h * 64 + db;
    *reinterpret_cast<short8*>(dst) = o0;
    *reinterpret_cast<short8*>(dst + 8) = o1;
}

// ---------------- launch ----------------
extern "C" void kernel_launch(void* const* d_in, const int* in_sizes, int n_in,
                              void* d_out, int out_size, void* d_ws, size_t ws_size,
                              hipStream_t stream)
{
    const float* src = (const float*)d_in[0];
    const float* Wq  = (const float*)d_in[1];
    const float* bq  = (const float*)d_in[2];
    const float* Wk  = (const float*)d_in[3];
    const float* bk  = (const float*)d_in[4];
    const float* Wv  = (const float*)d_in[5];
    const float* bv  = (const float*)d_in[6];
    const float* Wo  = (const float*)d_in[7];
    const float* bo  = (const float*)d_in[8];
    float* out = (float*)d_out;

    unsigned short* ws = (unsigned short*)d_ws;
    unsigned short* src_bf = ws;                                      // 16384*1024
    unsigned short* wqkv   = src_bf + (size_t)NTOK * EMB;             // 3*1024*1024 (Wq|Wk|Wv)
    unsigned short* wo_bf  = wqkv + (size_t)3 * EMB * EMB;            // 1024*1024 (contiguous after wqkv)
    unsigned short* qkv    = wo_bf + (size_t)EMB * EMB;               // 16384*3072
    unsigned short* ab     = qkv + (size_t)NTOK * 3 * EMB;            // 16384*1024
    float* bias_cat        = (float*)(ab + (size_t)NTOK * EMB);       // 3072 floats

    cvt_kernel<<<2048, 256, 0, stream>>>(src, src_bf, NTOK * EMB / 4);
    cvt4_kernel<<<2048, 256, 0, stream>>>(Wq, Wk, Wv, Wo, wqkv);  // fills wqkv then wo_bf
    bias_cat_kernel<<<12, 256, 0, stream>>>(bq, bk, bv, bias_cat);

    // fused QKV projection: [16384][3072] = src_bf * (Wq|Wk|Wv)^T
    gemm256<unsigned short><<<dim3(64 * 12), 512, 0, stream>>>(
        src_bf, wqkv, bias_cat, qkv, EMB, 3 * EMB, 64, 12);

    attn_kernel<<<NTOK / 4, 256, 0, stream>>>(qkv, ab);

    // output projection: [16384][1024]
    gemm256<float><<<dim3(64 * 4), 512, 0, stream>>>(
        ab, wo_bf, bo, out, EMB, EMB, 64, 4);
}

// Round 10
// 197.726 us; speedup vs baseline: 1.0153x; 1.0091x over previous
//
#include <hip/hip_runtime.h>
#include <stdint.h>
#include <stddef.h>

#define EMB 1024
#define NTOK 16384

typedef __attribute__((ext_vector_type(8))) short short8;
typedef __attribute__((ext_vector_type(4))) float floatx4;

__device__ __forceinline__ unsigned short f2bf(float f) {
    union { float f; unsigned int u; } v; v.f = f;
    unsigned int u = v.u;
    unsigned int r = (u + 0x7fffu + ((u >> 16) & 1u)) >> 16;
    return (unsigned short)r;
}
__device__ __forceinline__ float bf2f(unsigned short s) {
    union { unsigned int u; float f; } v; v.u = ((unsigned int)s) << 16;
    return v.f;
}

__device__ __forceinline__ void gload16(const void* g, void* l) {
    __builtin_amdgcn_global_load_lds(
        (const __attribute__((address_space(1))) void*)g,
        (__attribute__((address_space(3))) void*)l, 16, 0, 0);
}

#define SB0() __builtin_amdgcn_sched_barrier(0)

// opaque LDS b128 read: base VGPR (bytes) + compile-time immediate offset
#define DSR(dst, base, imm) \
    asm volatile("ds_read_b128 %0, %1 offset:%c2" : "=&v"(dst) : "v"(base), "i"(imm))

// ---------------- fp32 -> bf16 conversion ----------------
__global__ void cvt_kernel(const float* __restrict__ in,
                           unsigned short* __restrict__ out, int n4) {
    int idx = blockIdx.x * blockDim.x + threadIdx.x;
    int stride = gridDim.x * blockDim.x;
    for (int i = idx; i < n4; i += stride) {
        float4 f = reinterpret_cast<const float4*>(in)[i];
        ushort4 o;
        o.x = f2bf(f.x); o.y = f2bf(f.y); o.z = f2bf(f.z); o.w = f2bf(f.w);
        reinterpret_cast<ushort4*>(out)[i] = o;
    }
}

__global__ void cvt4_kernel(const float* __restrict__ s0, const float* __restrict__ s1,
                            const float* __restrict__ s2, const float* __restrict__ s3,
                            unsigned short* __restrict__ out) {
    int idx = blockIdx.x * blockDim.x + threadIdx.x;
    const int total = 4 << 18;
    int stride = gridDim.x * blockDim.x;
    for (int i = idx; i < total; i += stride) {
        int w = i >> 18, r = i & ((1 << 18) - 1);
        const float* s = (w == 0) ? s0 : (w == 1) ? s1 : (w == 2) ? s2 : s3;
        float4 f = reinterpret_cast<const float4*>(s)[r];
        ushort4 o;
        o.x = f2bf(f.x); o.y = f2bf(f.y); o.z = f2bf(f.z); o.w = f2bf(f.w);
        reinterpret_cast<ushort4*>(out)[i] = o;
    }
}

__global__ void bias_cat_kernel(const float* __restrict__ b0,
                                const float* __restrict__ b1,
                                const float* __restrict__ b2,
                                float* __restrict__ out) {
    int i = blockIdx.x * blockDim.x + threadIdx.x;
    float v = (i < 1024) ? b0[i] : (i < 2048 ? b1[i - 1024] : b2[i - 2048]);
    out[i] = v;
}

// ---------------- 256x256 8-phase bf16 GEMM (m201-style schedule) ----------------
// BK=64, 512 thr (8 waves 2Mx4N, per-wave 128x64), LDS 128 KB.
// Buffer b at b*32768 elems: A-half0 +0, A-half1 +8192, B-half0 +16384, B-half1 +24576.
// Half = 128 rows x 64 k; row = 128 B = 8 granules of 16 B, granule slot XOR-swizzled
// by (row&7) (conflict-free for both frag reads and linear gload_lds writes;
// global source pre-swizzled).
// Per K-tile 4 phases; phase = {ds_read quadrant frags; stage ONE half-tile;
// barrier; lgkmcnt(0); setprio(1); 16 MFMA; setprio(0); barrier}.
// Stage stream sigma: (t,ph0)->A0(t+1)  (t,ph1)->A1(t+1)   [into other buffer]
//                     (t,ph2)->B0(t+2)  (t,ph3)->B1(t+2)   [into CURRENT buffer;
//                      B slots freed after ph1 since B frags for ph3 are reg-held]
// ONE counted wait per tile: vmcnt(4) at ph3 end. Invariant: outstanding there
// <= {B0(t+1),B1(t+1) [from t-1], A0(t+1),A1(t+1), B0(t+2),B1(t+2)}; vmcnt(4)
// keeps only B0/B1(t+2) -> everything tile t+1 reads is landed. Prologue stages
// tile0 (4 halves) + B0/B1(tile1), vmcnt(4) -> tile0 landed.
__device__ __forceinline__ void store_val(float* C, size_t idx, float v) { C[idx] = v; }
__device__ __forceinline__ void store_val(unsigned short* C, size_t idx, float v) { C[idx] = f2bf(v); }

#define STG_A(h, bf, ko) do { \
    gload16(pA + (h)*KH + (ko),       &lds[(bf)*32768 + (h)*8192 + ldT]);  \
    gload16(pA + (h)*KH + (ko) + K64, &lds[(bf)*32768 + (h)*8192 + ldT2]); } while (0)
#define STG_B(h, bf, ko) do { \
    gload16(pB + (h)*KH + (ko),       &lds[(bf)*32768 + 16384 + (h)*8192 + ldT]);  \
    gload16(pB + (h)*KH + (ko) + K64, &lds[(bf)*32768 + 16384 + (h)*8192 + ldT2]); } while (0)

#define QMFMA(MB, NB, BF) do { \
    _Pragma("unroll") \
    for (int j_ = 0; j_ < 2; ++j_) { \
        _Pragma("unroll") \
        for (int i_ = 0; i_ < 4; ++i_) { \
            acc[(MB)+i_][(NB)+j_] = __builtin_amdgcn_mfma_f32_16x16x32_bf16(ak0[i_], BF[j_*2],   acc[(MB)+i_][(NB)+j_], 0, 0, 0); \
            acc[(MB)+i_][(NB)+j_] = __builtin_amdgcn_mfma_f32_16x16x32_bf16(ak1[i_], BF[j_*2+1], acc[(MB)+i_][(NB)+j_], 0, 0, 0); \
        } } } while (0)

template<typename OUT_T>
__global__ __launch_bounds__(512, 1)
void gemm8p(const unsigned short* __restrict__ A,
            const unsigned short* __restrict__ B,
            const float* __restrict__ bias,
            OUT_T* __restrict__ C,
            int K, int Nc, int grid_m)
{
    __shared__ unsigned short lds[65536];  // 128 KB

    // XCD-stripe mapping (r5): XCD owns (grid_m/8) m-tiles, n fastest.
    const int bid = blockIdx.x;
    const int x = bid & 7;
    const int w = bid >> 3;
    const int ms = grid_m >> 3;
    const int m0 = (x * ms + (w & (ms - 1))) * 256;
    const int n0 = (w / ms) * 256;

    const int tid = threadIdx.x, lane = tid & 63, wid = tid >> 6;
    const int wm = (wid >> 2) * 128, wn = (wid & 3) * 64;
    const int rr = lane & 15, ls = lane >> 4;
    const int sw0 = ((ls)     ^ (rr & 7)) << 4;   // kk=0 granule byte offset
    const int sw1 = ((4 | ls) ^ (rr & 7)) << 4;   // kk=1

    const unsigned ldsb = (unsigned)(uintptr_t)(void*)&lds[0];
    const unsigned aB0 = ldsb + (unsigned)((wm >> 7) * 16384 + rr * 128 + sw0);
    const unsigned aB1 = ldsb + (unsigned)((wm >> 7) * 16384 + rr * 128 + sw1);
    const unsigned bB0 = ldsb + 32768u + (unsigned)((wn >> 7) * 16384 + (wn & 64) * 128 + rr * 128 + sw0);
    const unsigned bB1 = ldsb + 32768u + (unsigned)((wn >> 7) * 16384 + (wn & 64) * 128 + rr * 128 + sw1);

    // staging: thread stages granules tid and tid+512 of each half-tile
    const int rT = tid >> 3, gst = tid & 7;
    const int gsrc = (gst ^ (rT & 7)) * 8;        // pre-swizzled source k-offset (elems)
    const unsigned short* pA = A + (size_t)(m0 + rT) * K + gsrc;
    const unsigned short* pB = B + (size_t)(n0 + rT) * K + gsrc;
    const int K64 = K * 64, KH = K * 128;
    const int ldT = tid * 8, ldT2 = (tid + 512) * 8;

    floatx4 acc[8][4];
#pragma unroll
    for (int i = 0; i < 8; ++i)
#pragma unroll
        for (int j = 0; j < 4; ++j)
            acc[i][j] = (floatx4){0.f, 0.f, 0.f, 0.f};

    const int NT = K >> 6;

    // ---- prologue: tile0 (all 4 halves) -> buf0 ; B0,B1(tile1) -> buf1 ----
    STG_A(0, 0, 0); STG_A(1, 0, 0); STG_B(0, 0, 0); STG_B(1, 0, 0);
    STG_B(0, 1, 64); STG_B(1, 1, 64);
    SB0();
    asm volatile("s_waitcnt vmcnt(4)");   // tile0 landed; B(1) in flight
    __builtin_amdgcn_s_barrier();
    SB0();

    short8 ak0[4], ak1[4], b0f[4], b1f[4];

    for (int t = 0; t < NT; ++t) {
        const int bfc = t & 1, bfn = bfc ^ 1;
        const unsigned cB = (unsigned)(bfc * 65536);
        const unsigned aC0 = aB0 + cB, aC1 = aB1 + cB;
        const unsigned bC0 = bB0 + cB, bC1 = bB1 + cB;
        const int ko1 = ((t + 1 < NT) ? (t + 1) : 0) * 64;
        const int ko2 = ((t + 2 < NT) ? (t + 2) : (t + 2 - NT)) * 64;

        // ===== ph0: read A-mh0(8) + B-nh0(4) ; stage A0(t+1) ; MFMA (mh0,nh0) =====
        DSR(ak0[0], aC0, 0);    DSR(ak0[1], aC0, 2048);
        DSR(ak0[2], aC0, 4096); DSR(ak0[3], aC0, 6144);
        DSR(ak1[0], aC1, 0);    DSR(ak1[1], aC1, 2048);
        DSR(ak1[2], aC1, 4096); DSR(ak1[3], aC1, 6144);
        DSR(b0f[0], bC0, 0);    DSR(b0f[1], bC1, 0);
        DSR(b0f[2], bC0, 2048); DSR(b0f[3], bC1, 2048);
        STG_A(0, bfn, ko1);
        SB0();
        __builtin_amdgcn_s_barrier();
        asm volatile("s_waitcnt lgkmcnt(0)");
        SB0();
        __builtin_amdgcn_s_setprio(1);
        QMFMA(0, 0, b0f);
        __builtin_amdgcn_s_setprio(0);
        SB0();
        __builtin_amdgcn_s_barrier();
        SB0();

        // ===== ph1: read B-nh1(4) ; stage A1(t+1) ; MFMA (mh0,nh1) =====
        DSR(b1f[0], bC0, 4096); DSR(b1f[1], bC1, 4096);
        DSR(b1f[2], bC0, 6144); DSR(b1f[3], bC1, 6144);
        STG_A(1, bfn, ko1);
        SB0();
        __builtin_amdgcn_s_barrier();
        asm volatile("s_waitcnt lgkmcnt(0)");
        SB0();
        __builtin_amdgcn_s_setprio(1);
        QMFMA(0, 2, b1f);
        __builtin_amdgcn_s_setprio(0);
        SB0();
        __builtin_amdgcn_s_barrier();
        SB0();

        // ===== ph2: read A-mh1(8) ; stage B0(t+2) into CUR buf ; MFMA (mh1,nh1) =====
        DSR(ak0[0], aC0, 8192);  DSR(ak0[1], aC0, 10240);
        DSR(ak0[2], aC0, 12288); DSR(ak0[3], aC0, 14336);
        DSR(ak1[0], aC1, 8192);  DSR(ak1[1], aC1, 10240);
        DSR(ak1[2], aC1, 12288); DSR(ak1[3], aC1, 14336);
        STG_B(0, bfc, ko2);
        SB0();
        __builtin_amdgcn_s_barrier();
        asm volatile("s_waitcnt lgkmcnt(0)");
        SB0();
        __builtin_amdgcn_s_setprio(1);
        QMFMA(4, 2, b1f);
        __builtin_amdgcn_s_setprio(0);
        SB0();
        __builtin_amdgcn_s_barrier();
        SB0();

        // ===== ph3: no reads ; stage B1(t+2) ; MFMA (mh1,nh0) ; vmcnt(4) =====
        STG_B(1, bfc, ko2);
        SB0();
        __builtin_amdgcn_s_barrier();
        SB0();
        __builtin_amdgcn_s_setprio(1);
        QMFMA(4, 0, b0f);
        __builtin_amdgcn_s_setprio(0);
        SB0();
        asm volatile("s_waitcnt vmcnt(4)");   // drains through A1(t+1); leaves B0/B1(t+2)
        __builtin_amdgcn_s_barrier();
        SB0();
    }

    // ---- epilogue ----
    const int cn  = lane & 15;
    const int cm4 = (lane >> 4) * 4;
    float bv[4];
#pragma unroll
    for (int j = 0; j < 4; ++j) bv[j] = bias[n0 + wn + j * 16 + cn];
#pragma unroll
    for (int ai = 0; ai < 8; ++ai) {
        const int row = m0 + wm + (ai >> 2) * 64 + (ai & 3) * 16 + cm4;
#pragma unroll
        for (int j = 0; j < 4; ++j) {
            const int col = n0 + wn + j * 16 + cn;
#pragma unroll
            for (int r = 0; r < 4; ++r)
                store_val(C, (size_t)(row + r) * Nc + col, acc[ai][j][r] + bv[j]);
        }
    }
}

// ---------------- per-token 16-head attention (wave per token) ----------------
#define ROWP 72

__global__ __launch_bounds__(256)
void attn_kernel(const unsigned short* __restrict__ QKV,
                 unsigned short* __restrict__ O)
{
    const int wave = threadIdx.x >> 6;
    const int lane = threadIdx.x & 63;
    const int n = blockIdx.x * 4 + wave;

    __shared__ unsigned short lq[4][16 * ROWP];
    __shared__ unsigned short lk[4][16 * ROWP];
    __shared__ unsigned short lv[4][16 * ROWP];
    __shared__ float lp[4][256];

    {
        const unsigned short* gq = QKV + (size_t)n * 3072;
        const unsigned short* gk = gq + 1024;
        const unsigned short* gv = gq + 2048;
        for (int t = lane; t < 128; t += 64) {
            int r = t >> 3, c = t & 7;
            *reinterpret_cast<short8*>(&lq[wave][r * ROWP + c * 8]) =
                *reinterpret_cast<const short8*>(gq + t * 8);
            *reinterpret_cast<short8*>(&lk[wave][r * ROWP + c * 8]) =
                *reinterpret_cast<const short8*>(gk + t * 8);
            *reinterpret_cast<short8*>(&lv[wave][r * ROWP + c * 8]) =
                *reinterpret_cast<const short8*>(gv + t * 8);
        }
    }
    __syncthreads();

    const int g = lane & 15;
    const int a = lane >> 4;

    float kf[64];
#pragma unroll
    for (int c2 = 0; c2 < 8; ++c2) {
        short8 kv = *reinterpret_cast<const short8*>(&lk[wave][g * ROWP + c2 * 8]);
#pragma unroll
        for (int e = 0; e < 8; ++e) kf[c2 * 8 + e] = bf2f((unsigned short)kv[e]);
    }

#pragma unroll
    for (int i = 0; i < 4; ++i) {
        const int h = i * 4 + a;
        float s = 0.f;
#pragma unroll
        for (int c2 = 0; c2 < 8; ++c2) {
            short8 qv = *reinterpret_cast<const short8*>(&lq[wave][h * ROWP + c2 * 8]);
#pragma unroll
            for (int e = 0; e < 8; ++e)
                s = fmaf(bf2f((unsigned short)qv[e]), kf[c2 * 8 + e], s);
        }
        s *= 0.125f;

        float m = s;
#pragma unroll
        for (int o = 1; o < 16; o <<= 1) m = fmaxf(m, __shfl_xor(m, o, 64));
        float p = expf(s - m);
        float sum = p;
#pragma unroll
        for (int o = 1; o < 16; o <<= 1) sum += __shfl_xor(sum, o, 64);
        lp[wave][h * 16 + g] = p / sum;
    }
    __syncthreads();

    const int h = lane >> 2;
    const int db = (lane & 3) * 16;
    float o[16];
#pragma unroll
    for (int e = 0; e < 16; ++e) o[e] = 0.f;

    for (int g2 = 0; g2 < 16; ++g2) {
        const float pw = lp[wave][h * 16 + g2];
        short8 v0 = *reinterpret_cast<const short8*>(&lv[wave][g2 * ROWP + db]);
        short8 v1 = *reinterpret_cast<const short8*>(&lv[wave][g2 * ROWP + db + 8]);
#pragma unroll
        for (int e = 0; e < 8; ++e) {
            o[e]     = fmaf(pw, bf2f((unsigned short)v0[e]), o[e]);
            o[8 + e] = fmaf(pw, bf2f((unsigned short)v1[e]), o[8 + e]);
        }
    }

    short8 o0, o1;
#pragma unroll
    for (int e = 0; e < 8; ++e) {
        o0[e] = (short)f2bf(o[e]);
        o1[e] = (short)f2bf(o[8 + e]);
    }
    unsigned short* dst = O + (size_t)n * EMB + h * 64 + db;
    *reinterpret_cast<short8*>(dst) = o0;
    *reinterpret_cast<short8*>(dst + 8) = o1;
}

// ---------------- launch ----------------
extern "C" void kernel_launch(void* const* d_in, const int* in_sizes, int n_in,
                              void* d_out, int out_size, void* d_ws, size_t ws_size,
                              hipStream_t stream)
{
    const float* src = (const float*)d_in[0];
    const float* Wq  = (const float*)d_in[1];
    const float* bq  = (const float*)d_in[2];
    const float* Wk  = (const float*)d_in[3];
    const float* bk  = (const float*)d_in[4];
    const float* Wv  = (const float*)d_in[5];
    const float* bv  = (const float*)d_in[6];
    const float* Wo  = (const float*)d_in[7];
    const float* bo  = (const float*)d_in[8];
    float* out = (float*)d_out;

    unsigned short* ws = (unsigned short*)d_ws;
    unsigned short* src_bf = ws;                                      // 16384*1024
    unsigned short* wqkv   = src_bf + (size_t)NTOK * EMB;             // 3*1024*1024 (Wq|Wk|Wv)
    unsigned short* wo_bf  = wqkv + (size_t)3 * EMB * EMB;            // 1024*1024
    unsigned short* qkv    = wo_bf + (size_t)EMB * EMB;               // 16384*3072
    unsigned short* ab     = qkv + (size_t)NTOK * 3 * EMB;            // 16384*1024
    float* bias_cat        = (float*)(ab + (size_t)NTOK * EMB);       // 3072 floats

    cvt_kernel<<<2048, 256, 0, stream>>>(src, src_bf, NTOK * EMB / 4);
    cvt4_kernel<<<2048, 256, 0, stream>>>(Wq, Wk, Wv, Wo, wqkv);  // fills wqkv then wo_bf
    bias_cat_kernel<<<12, 256, 0, stream>>>(bq, bk, bv, bias_cat);

    // fused QKV projection: [16384][3072] = src_bf * (Wq|Wk|Wv)^T
    gemm8p<unsigned short><<<dim3(64 * 12), 512, 0, stream>>>(
        src_bf, wqkv, bias_cat, qkv, EMB, 3 * EMB, 64);

    attn_kernel<<<NTOK / 4, 256, 0, stream>>>(qkv, ab);

    // output projection: [16384][1024]
    gemm8p<float><<<dim3(64 * 4), 512, 0, stream>>>(
        ab, wo_bf, bo, out, EMB, EMB, 64);
}